// Round 1
// baseline (12262.283 us; speedup 1.0000x reference)
//
#include <hip/hip_runtime.h>

// LightGCN: 3-layer propagation over a 150000-node graph, 4.8M COO edges, D=64.
// out = (e0 + A e0 + A^2 e0 + A^3 e0) / 4, A = COO(rows, cols, vals) scatter-add.

#define N_USERS 100000
#define N_ITEMS 50000
#define N_NODES 150000
#define N_EDGES 4800000
#define EMB_DIM 64

constexpr int NODE_FLOATS  = N_NODES * EMB_DIM;      // 9,600,000
constexpr int NODE_FLOAT4S = NODE_FLOATS / 4;        // 2,400,000
constexpr int USER_FLOAT4S = N_USERS * EMB_DIM / 4;  // 1,600,000

// Concat user/item embeddings into emb (ws buf0) and acc (d_out); zero nxt (ws buf1).
__global__ void init_kernel(const float* __restrict__ user_emb,
                            const float* __restrict__ item_emb,
                            float* __restrict__ emb,
                            float* __restrict__ acc,
                            float* __restrict__ nxt) {
    int i = blockIdx.x * blockDim.x + threadIdx.x;  // float4 index
    if (i >= NODE_FLOAT4S) return;
    float4 v;
    if (i < USER_FLOAT4S)
        v = ((const float4*)user_emb)[i];
    else
        v = ((const float4*)item_emb)[i - USER_FLOAT4S];
    ((float4*)emb)[i] = v;
    ((float4*)acc)[i] = v;
    ((float4*)nxt)[i] = make_float4(0.f, 0.f, 0.f, 0.f);
}

// COO SpMM: y[rows[e]] += vals[e] * x[cols[e]].  16 threads per edge, each
// handling 4 consecutive dims (float4 gather, 4 scalar atomics).
__global__ void spmm_kernel(const int* __restrict__ rows,
                            const int* __restrict__ cols,
                            const float* __restrict__ vals,
                            const float* __restrict__ x,
                            float* __restrict__ y) {
    unsigned tid = blockIdx.x * blockDim.x + threadIdx.x;
    unsigned e  = tid >> 4;        // edge index
    unsigned d4 = tid & 15u;       // which float4 of the 64-dim row
    if (e >= N_EDGES) return;
    int   r = rows[e];
    int   c = cols[e];
    float v = vals[e];
    float4 xv = ((const float4*)(x + (size_t)c * EMB_DIM))[d4];
    float* yp = y + (size_t)r * EMB_DIM + d4 * 4;
    atomicAdd(yp + 0, v * xv.x);
    atomicAdd(yp + 1, v * xv.y);
    atomicAdd(yp + 2, v * xv.z);
    atomicAdd(yp + 3, v * xv.w);
}

// acc = (acc + nxt) * scale; optionally zero zbuf (the buffer that becomes the
// next layer's scatter target).
__global__ void acc_kernel(float* __restrict__ acc,
                           const float* __restrict__ nxt,
                           float* __restrict__ zbuf,
                           int do_zero, float scale) {
    int i = blockIdx.x * blockDim.x + threadIdx.x;
    if (i >= NODE_FLOAT4S) return;
    float4 a = ((float4*)acc)[i];
    float4 n = ((const float4*)nxt)[i];
    a.x = (a.x + n.x) * scale;
    a.y = (a.y + n.y) * scale;
    a.z = (a.z + n.z) * scale;
    a.w = (a.w + n.w) * scale;
    ((float4*)acc)[i] = a;
    if (do_zero)
        ((float4*)zbuf)[i] = make_float4(0.f, 0.f, 0.f, 0.f);
}

extern "C" void kernel_launch(void* const* d_in, const int* in_sizes, int n_in,
                              void* d_out, int out_size, void* d_ws, size_t ws_size,
                              hipStream_t stream) {
    const int*   rows     = (const int*)d_in[0];
    const int*   cols     = (const int*)d_in[1];
    const float* vals     = (const float*)d_in[2];
    const float* user_emb = (const float*)d_in[3];
    const float* item_emb = (const float*)d_in[4];
    float* acc = (float*)d_out;                  // running sum, [N_NODES, 64]

    float* buf0 = (float*)d_ws;                  // 38.4 MB
    float* buf1 = buf0 + NODE_FLOATS;            // 38.4 MB

    const int EW_BLOCKS = (NODE_FLOAT4S + 255) / 256;
    const int SPMM_BLOCKS = (int)(((size_t)N_EDGES * 16 + 255) / 256);

    // acc = emb0 = concat(user, item); buf1 = 0
    init_kernel<<<EW_BLOCKS, 256, 0, stream>>>(user_emb, item_emb, buf0, acc, buf1);

    float* prev = buf0;
    float* next = buf1;
    for (int layer = 0; layer < 3; ++layer) {
        spmm_kernel<<<SPMM_BLOCKS, 256, 0, stream>>>(rows, cols, vals, prev, next);
        if (layer < 2) {
            // acc += next; zero prev (it becomes the next scatter target)
            acc_kernel<<<EW_BLOCKS, 256, 0, stream>>>(acc, next, prev, 1, 1.0f);
        } else {
            // final: acc = (acc + next) / 4
            acc_kernel<<<EW_BLOCKS, 256, 0, stream>>>(acc, next, prev, 0, 0.25f);
        }
        float* t = prev; prev = next; next = t;
    }
}

// Round 2
// 1353.844 us; speedup vs baseline: 9.0574x; 9.0574x over previous
//
#include <hip/hip_runtime.h>

// LightGCN: out = (e0 + A e0 + A^2 e0 + A^3 e0) / 4 over 150K nodes, 4.8M COO edges, D=64.
// R1: build CSR in-workspace each launch (histogram + scan + fill), then atomic-free
// SpMM: 16-lane group per row, shfl-broadcast edges, float4 gather, fused acc epilogue.

#define N_USERS 100000
#define N_ITEMS 50000
#define N_NODES 150000
#define N_EDGES 4800000
#define EMB_DIM 64

constexpr int NODE_FLOATS  = N_NODES * EMB_DIM;      // 9,600,000
constexpr int NODE_FLOAT4S = NODE_FLOATS / 4;        // 2,400,000
constexpr int USER_FLOAT4S = N_USERS * EMB_DIM / 4;  // 1,600,000

// ---------------- shared init ----------------
// emb0 = concat(user,item) -> buf0; acc = emb0 (d_out). No zeroing needed (CSR path
// fully overwrites outputs).
__global__ void init_kernel(const float* __restrict__ user_emb,
                            const float* __restrict__ item_emb,
                            float* __restrict__ emb,
                            float* __restrict__ acc) {
    int i = blockIdx.x * blockDim.x + threadIdx.x;
    if (i >= NODE_FLOAT4S) return;
    float4 v = (i < USER_FLOAT4S) ? ((const float4*)user_emb)[i]
                                  : ((const float4*)item_emb)[i - USER_FLOAT4S];
    ((float4*)emb)[i] = v;
    ((float4*)acc)[i] = v;
}

// ---------------- CSR build ----------------
__global__ void zero_counts_kernel(int* __restrict__ counts) {
    int i = blockIdx.x * blockDim.x + threadIdx.x;
    if (i < N_NODES) counts[i] = 0;
}

__global__ void hist_kernel(const int* __restrict__ rows, int* __restrict__ counts) {
    int e = blockIdx.x * blockDim.x + threadIdx.x;
    if (e < N_EDGES) atomicAdd(&counts[rows[e]], 1);
}

// Single block, 1024 threads. counts -> exclusive prefix (in place, becomes fill_pos)
// and row_ptr[0..N_NODES]. Wave-level shfl scan + cross-wave LDS combine: 2 syncs/chunk.
__global__ void scan_kernel(int* __restrict__ counts, int* __restrict__ row_ptr) {
    __shared__ int wsum[16];
    int tid  = threadIdx.x;
    int lane = tid & 63;
    int wave = tid >> 6;           // 0..15
    int carry = 0;                 // uniform across all threads
    for (int base = 0; base < N_NODES; base += 1024) {
        int i = base + tid;
        int v = (i < N_NODES) ? counts[i] : 0;
        // inclusive scan within wave
        int incl = v;
        #pragma unroll
        for (int off = 1; off < 64; off <<= 1) {
            int t = __shfl_up(incl, off);
            if (lane >= off) incl += t;
        }
        if (lane == 63) wsum[wave] = incl;
        __syncthreads();
        int wprefix = 0, tot = 0;
        #pragma unroll
        for (int w = 0; w < 16; ++w) {
            int s = wsum[w];
            if (w < wave) wprefix += s;
            tot += s;
        }
        int excl = carry + wprefix + incl - v;
        if (i < N_NODES) { row_ptr[i] = excl; counts[i] = excl; }
        carry += tot;
        __syncthreads();
    }
    if (tid == 0) row_ptr[N_NODES] = carry;   // == N_EDGES
}

// Scatter edges into CSR order. csr_ev[p] = (col, val) interleaved 8B records.
__global__ void fill_kernel(const int* __restrict__ rows,
                            const int* __restrict__ cols,
                            const float* __restrict__ vals,
                            int* __restrict__ fill_pos,
                            int2* __restrict__ csr_ev) {
    int e = blockIdx.x * blockDim.x + threadIdx.x;
    if (e >= N_EDGES) return;
    int r = rows[e];
    int p = atomicAdd(&fill_pos[r], 1);
    csr_ev[p] = make_int2(cols[e], __float_as_int(vals[e]));
}

// ---------------- CSR SpMM with fused acc epilogue ----------------
// One 16-lane group per row; lane handles 4 dims (float4). Edge (col,val) loaded
// cooperatively 16 at a time, broadcast via __shfl. No atomics.
// acc = (acc + y_row) * scale;  y stored only if y != nullptr (skipped on last layer).
__global__ void spmm_csr_kernel(const int* __restrict__ row_ptr,
                                const int2* __restrict__ csr_ev,
                                const float* __restrict__ x,
                                float* __restrict__ y,
                                float* __restrict__ acc,
                                float scale) {
    int gid    = blockIdx.x * blockDim.x + threadIdx.x;
    int lane16 = gid & 15;
    int row    = gid >> 4;
    if (row >= N_NODES) return;
    int waveBase = threadIdx.x & 48;   // group base lane within the 64-lane wave
    int beg = row_ptr[row], end = row_ptr[row + 1];

    float4 s = make_float4(0.f, 0.f, 0.f, 0.f);
    for (int j = beg; j < end; j += 16) {
        int n = end - j; if (n > 16) n = 16;
        int c = 0, vb = 0;
        if (lane16 < n) {
            int2 ev = csr_ev[j + lane16];
            c = ev.x; vb = ev.y;
        }
        for (int k = 0; k < n; ++k) {
            int   cc = __shfl(c,  waveBase + k);
            float vv = __int_as_float(__shfl(vb, waveBase + k));
            float4 xv = ((const float4*)(x + (size_t)cc * EMB_DIM))[lane16];
            s.x += vv * xv.x; s.y += vv * xv.y; s.z += vv * xv.z; s.w += vv * xv.w;
        }
    }

    size_t off4 = (size_t)row * (EMB_DIM / 4) + lane16;
    float4 a = ((const float4*)acc)[off4];
    a.x = (a.x + s.x) * scale; a.y = (a.y + s.y) * scale;
    a.z = (a.z + s.z) * scale; a.w = (a.w + s.w) * scale;
    ((float4*)acc)[off4] = a;
    if (y) ((float4*)y)[off4] = s;
}

// ---------------- fallback (R0 atomic path) kernels ----------------
__global__ void init3_kernel(const float* __restrict__ user_emb,
                             const float* __restrict__ item_emb,
                             float* __restrict__ emb,
                             float* __restrict__ acc,
                             float* __restrict__ nxt) {
    int i = blockIdx.x * blockDim.x + threadIdx.x;
    if (i >= NODE_FLOAT4S) return;
    float4 v = (i < USER_FLOAT4S) ? ((const float4*)user_emb)[i]
                                  : ((const float4*)item_emb)[i - USER_FLOAT4S];
    ((float4*)emb)[i] = v;
    ((float4*)acc)[i] = v;
    ((float4*)nxt)[i] = make_float4(0.f, 0.f, 0.f, 0.f);
}

__global__ void spmm_atomic_kernel(const int* __restrict__ rows,
                                   const int* __restrict__ cols,
                                   const float* __restrict__ vals,
                                   const float* __restrict__ x,
                                   float* __restrict__ y) {
    unsigned tid = blockIdx.x * blockDim.x + threadIdx.x;
    unsigned e  = tid >> 4;
    unsigned d4 = tid & 15u;
    if (e >= N_EDGES) return;
    int r = rows[e]; int c = cols[e]; float v = vals[e];
    float4 xv = ((const float4*)(x + (size_t)c * EMB_DIM))[d4];
    float* yp = y + (size_t)r * EMB_DIM + d4 * 4;
    atomicAdd(yp + 0, v * xv.x);
    atomicAdd(yp + 1, v * xv.y);
    atomicAdd(yp + 2, v * xv.z);
    atomicAdd(yp + 3, v * xv.w);
}

__global__ void acc_kernel(float* __restrict__ acc, const float* __restrict__ nxt,
                           float* __restrict__ zbuf, int do_zero, float scale) {
    int i = blockIdx.x * blockDim.x + threadIdx.x;
    if (i >= NODE_FLOAT4S) return;
    float4 a = ((float4*)acc)[i];
    float4 n = ((const float4*)nxt)[i];
    a.x = (a.x + n.x) * scale; a.y = (a.y + n.y) * scale;
    a.z = (a.z + n.z) * scale; a.w = (a.w + n.w) * scale;
    ((float4*)acc)[i] = a;
    if (do_zero) ((float4*)zbuf)[i] = make_float4(0.f, 0.f, 0.f, 0.f);
}

extern "C" void kernel_launch(void* const* d_in, const int* in_sizes, int n_in,
                              void* d_out, int out_size, void* d_ws, size_t ws_size,
                              hipStream_t stream) {
    const int*   rows     = (const int*)d_in[0];
    const int*   cols     = (const int*)d_in[1];
    const float* vals     = (const float*)d_in[2];
    const float* user_emb = (const float*)d_in[3];
    const float* item_emb = (const float*)d_in[4];
    float* acc = (float*)d_out;

    // ws layout (floats/ints, 4B units):
    //   buf0[9.6M] | buf1[9.6M] | row_ptr[N+1] | fill_pos[N] | csr_ev[2*4.8M]
    size_t need_u32 = (size_t)NODE_FLOATS * 2 + (N_NODES + 1) + N_NODES + (size_t)N_EDGES * 2;
    const int EW_BLOCKS   = (NODE_FLOAT4S + 255) / 256;
    const int EDGE_BLOCKS = (N_EDGES + 255) / 256;

    if (ws_size >= need_u32 * 4) {
        float* buf0     = (float*)d_ws;
        float* buf1     = buf0 + NODE_FLOATS;
        int*   row_ptr  = (int*)(buf1 + NODE_FLOATS);
        int*   fill_pos = row_ptr + (N_NODES + 1);
        int2*  csr_ev   = (int2*)(fill_pos + N_NODES);

        init_kernel<<<EW_BLOCKS, 256, 0, stream>>>(user_emb, item_emb, buf0, acc);

        // CSR build
        zero_counts_kernel<<<(N_NODES + 255) / 256, 256, 0, stream>>>(fill_pos);
        hist_kernel<<<EDGE_BLOCKS, 256, 0, stream>>>(rows, fill_pos);
        scan_kernel<<<1, 1024, 0, stream>>>(fill_pos, row_ptr);
        fill_kernel<<<EDGE_BLOCKS, 256, 0, stream>>>(rows, cols, vals, fill_pos, csr_ev);

        // 3 layers, acc fused; last layer scales by 1/4 and skips y-store.
        const int SPMM_BLOCKS = (N_NODES * 16 + 255) / 256;
        spmm_csr_kernel<<<SPMM_BLOCKS, 256, 0, stream>>>(row_ptr, csr_ev, buf0, buf1, acc, 1.0f);
        spmm_csr_kernel<<<SPMM_BLOCKS, 256, 0, stream>>>(row_ptr, csr_ev, buf1, buf0, acc, 1.0f);
        spmm_csr_kernel<<<SPMM_BLOCKS, 256, 0, stream>>>(row_ptr, csr_ev, buf0, nullptr, acc, 0.25f);
    } else {
        // fallback: R0 atomic path
        float* buf0 = (float*)d_ws;
        float* buf1 = buf0 + NODE_FLOATS;
        const int SPMM_BLOCKS = (int)(((size_t)N_EDGES * 16 + 255) / 256);
        init3_kernel<<<EW_BLOCKS, 256, 0, stream>>>(user_emb, item_emb, buf0, acc, buf1);
        float* prev = buf0; float* next = buf1;
        for (int layer = 0; layer < 3; ++layer) {
            spmm_atomic_kernel<<<SPMM_BLOCKS, 256, 0, stream>>>(rows, cols, vals, prev, next);
            if (layer < 2) acc_kernel<<<EW_BLOCKS, 256, 0, stream>>>(acc, next, prev, 1, 1.0f);
            else           acc_kernel<<<EW_BLOCKS, 256, 0, stream>>>(acc, next, prev, 0, 0.25f);
            float* t = prev; prev = next; next = t;
        }
    }
}

// Round 3
// 759.008 us; speedup vs baseline: 16.1557x; 1.7837x over previous
//
#include <hip/hip_runtime.h>

// LightGCN: out = (e0 + A e0 + A^2 e0 + A^3 e0) / 4 over 150K nodes, 4.8M COO edges, D=64.
// R2: (a) two-stage XCD-local CSR build (bucket scatter + per-bucket LDS hist/scan/scatter)
//     replacing the 330MB-write-inflated fill; (b) bf16 ping-pong layer buffers to halve
//     spmm gather/write traffic (acc stays fp32).

#define N_USERS 100000
#define N_ITEMS 50000
#define N_NODES 150000
#define N_EDGES 4800000
#define EMB_DIM 64

typedef unsigned short u16;
typedef unsigned int   u32;

constexpr int NODE_FLOATS  = N_NODES * EMB_DIM;      // 9,600,000
constexpr int NODE_FLOAT4S = NODE_FLOATS / 4;        // 2,400,000
constexpr int USER_FLOAT4S = N_USERS * EMB_DIM / 4;  // 1,600,000

constexpr int NB  = (N_NODES + 255) / 256;           // 586 row-buckets (rows>>8)
constexpr int NXG = 8;                               // XCD groups (blockIdx & 7)
constexpr int BX  = NB * NXG;                        // 4688 (bucket,xcd) segments
constexpr int EDGES_PER_BLOCK = 4096;
constexpr int ABLK = (N_EDGES + EDGES_PER_BLOCK - 1) / EDGES_PER_BLOCK;  // 1172

// ---- bf16 helpers (RNE) ----
static __device__ __forceinline__ float bf2f(u16 b) {
    return __uint_as_float(((u32)b) << 16);
}
static __device__ __forceinline__ u16 f2bf(float f) {
    u32 u = __float_as_uint(f);
    return (u16)((u + 0x7FFFu + ((u >> 16) & 1u)) >> 16);
}

// ---------------- init: buf0 = bf16(e0), acc = fp32 e0 ----------------
__global__ void init_kernel(const float* __restrict__ user_emb,
                            const float* __restrict__ item_emb,
                            u16* __restrict__ emb,
                            float* __restrict__ acc) {
    int i = blockIdx.x * blockDim.x + threadIdx.x;
    if (i >= NODE_FLOAT4S) return;
    float4 v = (i < USER_FLOAT4S) ? ((const float4*)user_emb)[i]
                                  : ((const float4*)item_emb)[i - USER_FLOAT4S];
    ((float4*)acc)[i] = v;
    ushort4 o;
    o.x = f2bf(v.x); o.y = f2bf(v.y); o.z = f2bf(v.z); o.w = f2bf(v.w);
    ((ushort4*)emb)[i] = o;
}

// ---------------- (bucket, xcd-group) histogram with LDS pre-aggregation ----------------
__global__ void bhist_kernel(const int* __restrict__ rows, int* __restrict__ bx_cnt) {
    __shared__ int cnt[NB];
    for (int i = threadIdx.x; i < NB; i += 256) cnt[i] = 0;
    __syncthreads();
    int x = blockIdx.x & (NXG - 1);
    int base = blockIdx.x * EDGES_PER_BLOCK;
    for (int t = threadIdx.x; t < EDGES_PER_BLOCK; t += 256) {
        int e = base + t;
        if (e < N_EDGES) atomicAdd(&cnt[rows[e] >> 8], 1);
    }
    __syncthreads();
    for (int i = threadIdx.x; i < NB; i += 256) {
        int c = cnt[i];
        if (c) atomicAdd(&bx_cnt[i * NXG + x], c);
    }
}

// ---------------- exclusive scan over BX=4688 counts (single block) ----------------
// bx_start[i] compact (read by stageB / bucket bounds); bx_pos[i*16] padded atomic frontiers.
__global__ void bscan_kernel(const int* __restrict__ bx_cnt,
                             int* __restrict__ bx_start,
                             int* __restrict__ bx_pos) {
    __shared__ int wsum[16];
    int tid = threadIdx.x;
    int lane = tid & 63;
    int wave = tid >> 6;
    int carry = 0;
    for (int base = 0; base < BX; base += 1024) {
        int i = base + tid;
        int v = (i < BX) ? bx_cnt[i] : 0;
        int incl = v;
        #pragma unroll
        for (int off = 1; off < 64; off <<= 1) {
            int t = __shfl_up(incl, off);
            if (lane >= off) incl += t;
        }
        if (lane == 63) wsum[wave] = incl;
        __syncthreads();
        int wprefix = 0, tot = 0;
        #pragma unroll
        for (int w = 0; w < 16; ++w) {
            int s = wsum[w];
            if (w < wave) wprefix += s;
            tot += s;
        }
        int excl = carry + wprefix + incl - v;
        if (i < BX) { bx_start[i] = excl; bx_pos[i * 16] = excl; }
        carry += tot;
        __syncthreads();
    }
    if (tid == 0) bx_start[BX] = carry;   // == N_EDGES
}

// ---------------- stage A: scatter edges into (bucket, xcd) segments ----------------
// record: {(rowlow<<24) | col, val_bits}; frontier lines are XCD-private -> fully filled.
__global__ void stageA_kernel(const int* __restrict__ rows,
                              const int* __restrict__ cols,
                              const float* __restrict__ vals,
                              int* __restrict__ bx_pos,
                              int2* __restrict__ stage) {
    int x = blockIdx.x & (NXG - 1);
    int base = blockIdx.x * EDGES_PER_BLOCK;
    for (int t = threadIdx.x; t < EDGES_PER_BLOCK; t += 256) {
        int e = base + t;
        if (e >= N_EDGES) continue;
        int r = rows[e];
        int p = atomicAdd(&bx_pos[((r >> 8) * NXG + x) * 16], 1);
        stage[p] = make_int2(((r & 255) << 24) | cols[e], __float_as_int(vals[e]));
    }
}

// ---------------- stage B: per-bucket exact CSR via LDS hist+scan+scatter ----------------
// One block per bucket. Also emits row_ptr for the bucket's 256 rows.
__global__ void stageB_kernel(const int* __restrict__ bx_start,
                              const int2* __restrict__ stage,
                              int* __restrict__ row_ptr,
                              int2* __restrict__ csr_ev) {
    __shared__ int cnt[256];
    __shared__ int pos[256];
    __shared__ int ws4[4];
    int b = blockIdx.x;
    int beg = bx_start[b * NXG];
    int end = bx_start[(b + 1) * NXG];
    int tid = threadIdx.x;
    cnt[tid] = 0;
    __syncthreads();
    for (int s = beg + tid; s < end; s += 256)
        atomicAdd(&cnt[((u32)stage[s].x) >> 24], 1);
    __syncthreads();
    // exclusive scan of cnt[256]
    int lane = tid & 63, wave = tid >> 6;
    int v = cnt[tid], incl = v;
    #pragma unroll
    for (int off = 1; off < 64; off <<= 1) {
        int t = __shfl_up(incl, off);
        if (lane >= off) incl += t;
    }
    if (lane == 63) ws4[wave] = incl;
    __syncthreads();
    int wpref = 0;
    #pragma unroll
    for (int w = 0; w < 4; ++w) if (w < wave) wpref += ws4[w];
    int excl = wpref + incl - v;
    int grow = b * 256 + tid;
    if (grow < N_NODES) row_ptr[grow] = beg + excl;
    if (b == NB - 1 && tid == 0) row_ptr[N_NODES] = end;
    pos[tid] = excl;
    __syncthreads();
    for (int s = beg + tid; s < end; s += 256) {
        int2 rec = stage[s];
        int rl = ((u32)rec.x) >> 24;
        int p = beg + atomicAdd(&pos[rl], 1);
        csr_ev[p] = make_int2(rec.x & 0xFFFFFF, rec.y);
    }
}

// ---------------- CSR SpMM, bf16 x/y, fp32 acc fused ----------------
__global__ void spmm_csr_kernel(const int* __restrict__ row_ptr,
                                const int2* __restrict__ csr_ev,
                                const u16* __restrict__ x,
                                u16* __restrict__ y,
                                float* __restrict__ acc,
                                float scale) {
    int gid = blockIdx.x * blockDim.x + threadIdx.x;
    int lane16 = gid & 15;
    int row = gid >> 4;
    if (row >= N_NODES) return;
    int waveBase = threadIdx.x & 48;
    int beg = row_ptr[row], end = row_ptr[row + 1];

    float4 s = make_float4(0.f, 0.f, 0.f, 0.f);
    for (int j = beg; j < end; j += 16) {
        int n = end - j; if (n > 16) n = 16;
        int c = 0, vb = 0;
        if (lane16 < n) {
            int2 ev = csr_ev[j + lane16];
            c = ev.x; vb = ev.y;
        }
        for (int k = 0; k < n; ++k) {
            int   cc = __shfl(c,  waveBase + k);
            float vv = __int_as_float(__shfl(vb, waveBase + k));
            ushort4 xv = ((const ushort4*)(x + (size_t)cc * EMB_DIM))[lane16];
            s.x += vv * bf2f(xv.x);
            s.y += vv * bf2f(xv.y);
            s.z += vv * bf2f(xv.z);
            s.w += vv * bf2f(xv.w);
        }
    }

    size_t o4 = (size_t)row * (EMB_DIM / 4) + lane16;
    float4 a = ((const float4*)acc)[o4];
    a.x = (a.x + s.x) * scale; a.y = (a.y + s.y) * scale;
    a.z = (a.z + s.z) * scale; a.w = (a.w + s.w) * scale;
    ((float4*)acc)[o4] = a;
    if (y) {
        ushort4 o;
        o.x = f2bf(s.x); o.y = f2bf(s.y); o.z = f2bf(s.z); o.w = f2bf(s.w);
        ((ushort4*)y)[o4] = o;
    }
}

// ---------------- fallback (R0 atomic path) ----------------
__global__ void init3_kernel(const float* __restrict__ user_emb,
                             const float* __restrict__ item_emb,
                             float* __restrict__ emb,
                             float* __restrict__ acc,
                             float* __restrict__ nxt) {
    int i = blockIdx.x * blockDim.x + threadIdx.x;
    if (i >= NODE_FLOAT4S) return;
    float4 v = (i < USER_FLOAT4S) ? ((const float4*)user_emb)[i]
                                  : ((const float4*)item_emb)[i - USER_FLOAT4S];
    ((float4*)emb)[i] = v;
    ((float4*)acc)[i] = v;
    ((float4*)nxt)[i] = make_float4(0.f, 0.f, 0.f, 0.f);
}

__global__ void spmm_atomic_kernel(const int* __restrict__ rows,
                                   const int* __restrict__ cols,
                                   const float* __restrict__ vals,
                                   const float* __restrict__ x,
                                   float* __restrict__ y) {
    unsigned tid = blockIdx.x * blockDim.x + threadIdx.x;
    unsigned e  = tid >> 4;
    unsigned d4 = tid & 15u;
    if (e >= N_EDGES) return;
    int r = rows[e]; int c = cols[e]; float v = vals[e];
    float4 xv = ((const float4*)(x + (size_t)c * EMB_DIM))[d4];
    float* yp = y + (size_t)r * EMB_DIM + d4 * 4;
    atomicAdd(yp + 0, v * xv.x);
    atomicAdd(yp + 1, v * xv.y);
    atomicAdd(yp + 2, v * xv.z);
    atomicAdd(yp + 3, v * xv.w);
}

__global__ void acc_kernel(float* __restrict__ acc, const float* __restrict__ nxt,
                           float* __restrict__ zbuf, int do_zero, float scale) {
    int i = blockIdx.x * blockDim.x + threadIdx.x;
    if (i >= NODE_FLOAT4S) return;
    float4 a = ((float4*)acc)[i];
    float4 n = ((const float4*)nxt)[i];
    a.x = (a.x + n.x) * scale; a.y = (a.y + n.y) * scale;
    a.z = (a.z + n.z) * scale; a.w = (a.w + n.w) * scale;
    ((float4*)acc)[i] = a;
    if (do_zero) ((float4*)zbuf)[i] = make_float4(0.f, 0.f, 0.f, 0.f);
}

extern "C" void kernel_launch(void* const* d_in, const int* in_sizes, int n_in,
                              void* d_out, int out_size, void* d_ws, size_t ws_size,
                              hipStream_t stream) {
    const int*   rows     = (const int*)d_in[0];
    const int*   cols     = (const int*)d_in[1];
    const float* vals     = (const float*)d_in[2];
    const float* user_emb = (const float*)d_in[3];
    const float* item_emb = (const float*)d_in[4];
    float* acc = (float*)d_out;

    // ws layout (u32 units):
    //   buf0 bf16 [4.8M u32] | stage int2 [9.6M u32]  (buf1 bf16 aliases stage[0:4.8M])
    //   | csr_ev int2 [9.6M u32] | row_ptr [150001] | bx_cnt [4688] | bx_start [4689]
    //   | bx_pos [4688*16]
    constexpr size_t U_BUF  = (size_t)NODE_FLOATS / 2;   // 4.8M
    constexpr size_t U_EV   = (size_t)N_EDGES * 2;       // 9.6M
    size_t need_u32 = U_BUF + U_EV + U_EV + (N_NODES + 1) + BX + (BX + 1) + (size_t)BX * 16;

    const int EW_BLOCKS = (NODE_FLOAT4S + 255) / 256;

    if (ws_size >= need_u32 * 4) {
        u32* W = (u32*)d_ws;
        u16*  buf0     = (u16*)W;
        int2* stage    = (int2*)(W + U_BUF);
        u16*  buf1     = (u16*)(W + U_BUF);              // aliases stage (dead after stageB)
        int2* csr_ev   = (int2*)(W + U_BUF + U_EV);
        int*  row_ptr  = (int*)(W + U_BUF + 2 * U_EV);
        int*  bx_cnt   = row_ptr + (N_NODES + 1);
        int*  bx_start = bx_cnt + BX;
        int*  bx_pos   = bx_start + (BX + 1);

        hipMemsetAsync(bx_cnt, 0, BX * sizeof(int), stream);
        init_kernel<<<EW_BLOCKS, 256, 0, stream>>>(user_emb, item_emb, buf0, acc);

        bhist_kernel<<<ABLK, 256, 0, stream>>>(rows, bx_cnt);
        bscan_kernel<<<1, 1024, 0, stream>>>(bx_cnt, bx_start, bx_pos);
        stageA_kernel<<<ABLK, 256, 0, stream>>>(rows, cols, vals, bx_pos, stage);
        stageB_kernel<<<NB, 256, 0, stream>>>(bx_start, stage, row_ptr, csr_ev);

        const int SPMM_BLOCKS = (N_NODES * 16 + 255) / 256;
        spmm_csr_kernel<<<SPMM_BLOCKS, 256, 0, stream>>>(row_ptr, csr_ev, buf0, buf1, acc, 1.0f);
        spmm_csr_kernel<<<SPMM_BLOCKS, 256, 0, stream>>>(row_ptr, csr_ev, buf1, buf0, acc, 1.0f);
        spmm_csr_kernel<<<SPMM_BLOCKS, 256, 0, stream>>>(row_ptr, csr_ev, buf0, nullptr, acc, 0.25f);
    } else {
        // fallback: R0 atomic path (needs 76.8MB ws)
        float* buf0 = (float*)d_ws;
        float* buf1 = buf0 + NODE_FLOATS;
        const int SPMM_BLOCKS = (int)(((size_t)N_EDGES * 16 + 255) / 256);
        init3_kernel<<<EW_BLOCKS, 256, 0, stream>>>(user_emb, item_emb, buf0, acc, buf1);
        float* prev = buf0; float* next = buf1;
        for (int layer = 0; layer < 3; ++layer) {
            spmm_atomic_kernel<<<SPMM_BLOCKS, 256, 0, stream>>>(rows, cols, vals, prev, next);
            if (layer < 2) acc_kernel<<<EW_BLOCKS, 256, 0, stream>>>(acc, next, prev, 1, 1.0f);
            else           acc_kernel<<<EW_BLOCKS, 256, 0, stream>>>(acc, next, prev, 0, 0.25f);
            float* t = prev; prev = next; next = t;
        }
    }
}

// Round 4
// 563.144 us; speedup vs baseline: 21.7747x; 1.3478x over previous
//
#include <hip/hip_runtime.h>

// LightGCN: out = (e0 + A e0 + A^2 e0 + A^3 e0) / 4 over 150K nodes, 4.8M COO edges, D=64.
// R3: block-local LDS counting sort (stageA2) + per-bucket LDS row sort (stageB2),
// fixed-capacity segments (no global hist/scan), 6B edge records (col u32 + bf16 val).
// Evidence from R2: partial-line scattered writes inflate ~5x (195MB for 38.4MB) —
// only wave-coalesced full-line bursts from LDS-assembled runs avoid it.

#define N_USERS 100000
#define N_ITEMS 50000
#define N_NODES 150000
#define N_EDGES 4800000
#define EMB_DIM 64

typedef unsigned short u16;
typedef unsigned int   u32;

constexpr int NODE_FLOATS  = N_NODES * EMB_DIM;      // 9,600,000
constexpr int NODE_FLOAT4S = NODE_FLOATS / 4;        // 2,400,000
constexpr int USER_FLOAT4S = N_USERS * EMB_DIM / 4;  // 1,600,000

constexpr int NB   = (N_NODES + 255) / 256;          // 586 buckets (256 rows each)
constexpr int NXG  = 8;                              // XCD groups (blockIdx & 7)
constexpr int SEG  = NB * NXG;                       // 4688 (bucket,x) segments
constexpr int CAP1 = 1280;                           // per-segment capacity (mean 1028, +8σ)
constexpr int EPB  = 6144;                           // edges per stageA2 block
constexpr int ABLK2 = (N_EDGES + EPB - 1) / EPB;     // 782
constexpr int SB_CAP = 8960;                         // stageB2 LDS records (mean 8192, +8.5σ)

// ---- bf16 helpers (RNE) ----
static __device__ __forceinline__ float bf2f(u16 b) {
    return __uint_as_float(((u32)b) << 16);
}
static __device__ __forceinline__ u16 f2bf(float f) {
    u32 u = __float_as_uint(f);
    return (u16)((u + 0x7FFFu + ((u >> 16) & 1u)) >> 16);
}

// ---------------- init: buf0 = bf16(e0), acc = fp32 e0 ----------------
__global__ void init_kernel(const float* __restrict__ user_emb,
                            const float* __restrict__ item_emb,
                            u16* __restrict__ emb,
                            float* __restrict__ acc) {
    int i = blockIdx.x * blockDim.x + threadIdx.x;
    if (i >= NODE_FLOAT4S) return;
    float4 v = (i < USER_FLOAT4S) ? ((const float4*)user_emb)[i]
                                  : ((const float4*)item_emb)[i - USER_FLOAT4S];
    ((float4*)acc)[i] = v;
    ushort4 o;
    o.x = f2bf(v.x); o.y = f2bf(v.y); o.z = f2bf(v.z); o.w = f2bf(v.w);
    ((ushort4*)emb)[i] = o;
}

// ---------------- init segment frontiers ----------------
__global__ void init_ptrs_kernel(int* __restrict__ bx_pos, int* __restrict__ csr_cursor) {
    int i = blockIdx.x * blockDim.x + threadIdx.x;
    if (i < SEG) bx_pos[i * 16] = i * CAP1;
    if (i == 0) csr_cursor[0] = 0;
}

// ---------------- stage A2: block-local counting sort by bucket ----------------
__global__ void stageA2_kernel(const int* __restrict__ rows,
                               const int* __restrict__ cols,
                               const float* __restrict__ vals,
                               int* __restrict__ bx_pos,
                               u32* __restrict__ stage_key,
                               u16* __restrict__ stage_val) {
    __shared__ u32 lkey[EPB];          // 24 KB
    __shared__ u16 lval[EPB];          // 12 KB
    __shared__ u16 lbkt[EPB];          // 12 KB
    __shared__ int hist[NB];
    __shared__ int hstart[NB];
    __shared__ int hcur[NB];
    __shared__ int gbase[NB];          // 4 x 2.34 KB
    __shared__ int ws4[4];

    const int tid  = threadIdx.x;
    const int base = blockIdx.x * EPB;
    const int cnt  = min(EPB, N_EDGES - base);
    const int x    = blockIdx.x & (NXG - 1);

    for (int i = tid; i < NB; i += 256) hist[i] = 0;
    __syncthreads();

    // pass 1: bucket histogram (batched loads for MLP)
    for (int k = 0; k < EPB / 256; k += 8) {
        int rbuf[8];
        #pragma unroll
        for (int q = 0; q < 8; ++q) {
            int idx = (k + q) * 256 + tid;
            rbuf[q] = (idx < cnt) ? rows[base + idx] : -1;
        }
        #pragma unroll
        for (int q = 0; q < 8; ++q)
            if (rbuf[q] >= 0) atomicAdd(&hist[rbuf[q] >> 8], 1);
    }
    __syncthreads();

    // exclusive scan hist -> hstart, hcur (256-wide chunks with carry)
    const int lane = tid & 63, wave = tid >> 6;
    int carry = 0;
    for (int c0 = 0; c0 < NB; c0 += 256) {
        int i = c0 + tid;
        int v = (i < NB) ? hist[i] : 0;
        int incl = v;
        #pragma unroll
        for (int off = 1; off < 64; off <<= 1) {
            int t = __shfl_up(incl, off);
            if (lane >= off) incl += t;
        }
        if (lane == 63) ws4[wave] = incl;
        __syncthreads();
        int wpref = 0, tot = 0;
        #pragma unroll
        for (int w = 0; w < 4; ++w) { int s = ws4[w]; if (w < wave) wpref += s; tot += s; }
        int excl = carry + wpref + incl - v;
        if (i < NB) { hstart[i] = excl; hcur[i] = excl; }
        carry += tot;
        __syncthreads();
    }

    // pass 2: scatter records into LDS sorted-by-bucket order
    for (int k = 0; k < EPB / 256; k += 8) {
        int rb[8], cb[8]; float vb[8];
        #pragma unroll
        for (int q = 0; q < 8; ++q) {
            int idx = (k + q) * 256 + tid;
            if (idx < cnt) { rb[q] = rows[base + idx]; cb[q] = cols[base + idx]; vb[q] = vals[base + idx]; }
            else rb[q] = -1;
        }
        #pragma unroll
        for (int q = 0; q < 8; ++q) {
            if (rb[q] < 0) continue;
            int b = rb[q] >> 8;
            int p = atomicAdd(&hcur[b], 1);
            lkey[p] = ((u32)(rb[q] & 255) << 24) | (u32)cb[q];
            lval[p] = f2bf(vb[q]);
            lbkt[p] = (u16)b;
        }
    }
    __syncthreads();

    // bulk-reserve one chunk per nonempty bucket (1 global atomic per bucket)
    for (int i = tid; i < NB; i += 256) {
        int n = hist[i];
        if (n) {
            int seg = i * NXG + x;
            int p = atomicAdd(&bx_pos[seg * 16], n);
            gbase[i] = (p + n <= (seg + 1) * CAP1) ? p : -1;   // overflow guard (never hit)
        }
    }
    __syncthreads();

    // coalesced copy: consecutive i -> consecutive dst within each bucket run
    for (int i = tid; i < cnt; i += 256) {
        int b  = lbkt[i];
        int gb = gbase[b];
        if (gb >= 0) {
            int d = gb + (i - hstart[b]);
            stage_key[d] = lkey[i];
            stage_val[d] = lval[i];
        }
    }
}

// ---------------- stage B2: per-bucket row sort in LDS, contiguous CSR out ----------------
__global__ void stageB2_kernel(const int* __restrict__ bx_pos,
                               const u32* __restrict__ stage_key,
                               const u16* __restrict__ stage_val,
                               int* __restrict__ csr_cursor,
                               u32* __restrict__ csr_col,
                               u16* __restrict__ csr_val,
                               int* __restrict__ row_beg,
                               int* __restrict__ row_cnt) {
    __shared__ u32 skey[SB_CAP];       // 35.8 KB
    __shared__ u16 sval[SB_CAP];       // 17.9 KB
    __shared__ int rhist[256], rstart[256], rcur[256];
    __shared__ int ws4[4];
    __shared__ int sbase_sh;

    const int b   = blockIdx.x;
    const int tid = threadIdx.x;
    rhist[tid] = 0;
    __syncthreads();

    // pass 1: row-within-bucket histogram over the 8 x-segments
    for (int xx = 0; xx < NXG; ++xx) {
        int seg = b * NXG + xx;
        int sb  = seg * CAP1;
        int n   = min(bx_pos[seg * 16] - sb, CAP1);
        for (int i = tid; i < n; i += 256)
            atomicAdd(&rhist[stage_key[sb + i] >> 24], 1);
    }
    __syncthreads();

    // exclusive scan of rhist[256]
    const int lane = tid & 63, wave = tid >> 6;
    int v = rhist[tid], incl = v;
    #pragma unroll
    for (int off = 1; off < 64; off <<= 1) {
        int t = __shfl_up(incl, off);
        if (lane >= off) incl += t;
    }
    if (lane == 63) ws4[wave] = incl;
    __syncthreads();
    int wpref = 0, total = 0;
    #pragma unroll
    for (int w = 0; w < 4; ++w) { int s = ws4[w]; if (w < wave) wpref += s; total += s; }
    int excl = wpref + incl - v;
    rstart[tid] = excl;
    rcur[tid]   = excl;
    if (tid == 0) sbase_sh = atomicAdd(csr_cursor, total);
    __syncthreads();

    // pass 2: scatter into LDS row-sorted order
    for (int xx = 0; xx < NXG; ++xx) {
        int seg = b * NXG + xx;
        int sb  = seg * CAP1;
        int n   = min(bx_pos[seg * 16] - sb, CAP1);
        for (int i = tid; i < n; i += 256) {
            u32 key = stage_key[sb + i];
            u16 val = stage_val[sb + i];
            int p = atomicAdd(&rcur[key >> 24], 1);
            if (p < SB_CAP) { skey[p] = key & 0x00FFFFFFu; sval[p] = val; }
        }
    }
    __syncthreads();

    // contiguous, fully-coalesced CSR write
    int sbase = sbase_sh;
    int tcap  = min(total, SB_CAP);
    for (int i = tid; i < tcap; i += 256) {
        csr_col[sbase + i] = skey[i];
        csr_val[sbase + i] = sval[i];
    }
    int grow = b * 256 + tid;
    if (grow < N_NODES) {
        row_beg[grow] = sbase + rstart[tid];
        row_cnt[grow] = rhist[tid];
    }
}

// ---------------- CSR SpMM, bf16 x/y/vals, fp32 acc fused ----------------
__global__ void spmm_csr_kernel(const int* __restrict__ row_beg,
                                const int* __restrict__ row_cnt,
                                const u32* __restrict__ csr_col,
                                const u16* __restrict__ csr_val,
                                const u16* __restrict__ x,
                                u16* __restrict__ y,
                                float* __restrict__ acc,
                                float scale) {
    int gid    = blockIdx.x * blockDim.x + threadIdx.x;
    int lane16 = gid & 15;
    int row    = gid >> 4;
    if (row >= N_NODES) return;
    int waveBase = threadIdx.x & 48;
    int beg = row_beg[row];
    int m   = row_cnt[row];

    float4 s = make_float4(0.f, 0.f, 0.f, 0.f);
    for (int j = 0; j < m; j += 16) {
        int n = m - j; if (n > 16) n = 16;
        int c = 0, vb = 0;
        if (lane16 < n) {
            c  = (int)csr_col[beg + j + lane16];
            vb = (int)csr_val[beg + j + lane16];
        }
        for (int k = 0; k < n; ++k) {
            int   cc = __shfl(c,  waveBase + k);
            float vv = bf2f((u16)__shfl(vb, waveBase + k));
            ushort4 xv = ((const ushort4*)(x + (size_t)cc * EMB_DIM))[lane16];
            s.x += vv * bf2f(xv.x);
            s.y += vv * bf2f(xv.y);
            s.z += vv * bf2f(xv.z);
            s.w += vv * bf2f(xv.w);
        }
    }

    size_t o4 = (size_t)row * (EMB_DIM / 4) + lane16;
    float4 a = ((const float4*)acc)[o4];
    a.x = (a.x + s.x) * scale; a.y = (a.y + s.y) * scale;
    a.z = (a.z + s.z) * scale; a.w = (a.w + s.w) * scale;
    ((float4*)acc)[o4] = a;
    if (y) {
        ushort4 o;
        o.x = f2bf(s.x); o.y = f2bf(s.y); o.z = f2bf(s.z); o.w = f2bf(s.w);
        ((ushort4*)y)[o4] = o;
    }
}

// ---------------- fallback (R0 atomic path) ----------------
__global__ void init3_kernel(const float* __restrict__ user_emb,
                             const float* __restrict__ item_emb,
                             float* __restrict__ emb,
                             float* __restrict__ acc,
                             float* __restrict__ nxt) {
    int i = blockIdx.x * blockDim.x + threadIdx.x;
    if (i >= NODE_FLOAT4S) return;
    float4 v = (i < USER_FLOAT4S) ? ((const float4*)user_emb)[i]
                                  : ((const float4*)item_emb)[i - USER_FLOAT4S];
    ((float4*)emb)[i] = v;
    ((float4*)acc)[i] = v;
    ((float4*)nxt)[i] = make_float4(0.f, 0.f, 0.f, 0.f);
}

__global__ void spmm_atomic_kernel(const int* __restrict__ rows,
                                   const int* __restrict__ cols,
                                   const float* __restrict__ vals,
                                   const float* __restrict__ x,
                                   float* __restrict__ y) {
    unsigned tid = blockIdx.x * blockDim.x + threadIdx.x;
    unsigned e  = tid >> 4;
    unsigned d4 = tid & 15u;
    if (e >= N_EDGES) return;
    int r = rows[e]; int c = cols[e]; float v = vals[e];
    float4 xv = ((const float4*)(x + (size_t)c * EMB_DIM))[d4];
    float* yp = y + (size_t)r * EMB_DIM + d4 * 4;
    atomicAdd(yp + 0, v * xv.x);
    atomicAdd(yp + 1, v * xv.y);
    atomicAdd(yp + 2, v * xv.z);
    atomicAdd(yp + 3, v * xv.w);
}

__global__ void acc_kernel(float* __restrict__ acc, const float* __restrict__ nxt,
                           float* __restrict__ zbuf, int do_zero, float scale) {
    int i = blockIdx.x * blockDim.x + threadIdx.x;
    if (i >= NODE_FLOAT4S) return;
    float4 a = ((float4*)acc)[i];
    float4 n = ((const float4*)nxt)[i];
    a.x = (a.x + n.x) * scale; a.y = (a.y + n.y) * scale;
    a.z = (a.z + n.z) * scale; a.w = (a.w + n.w) * scale;
    ((float4*)acc)[i] = a;
    if (do_zero) ((float4*)zbuf)[i] = make_float4(0.f, 0.f, 0.f, 0.f);
}

extern "C" void kernel_launch(void* const* d_in, const int* in_sizes, int n_in,
                              void* d_out, int out_size, void* d_ws, size_t ws_size,
                              hipStream_t stream) {
    const int*   rows     = (const int*)d_in[0];
    const int*   cols     = (const int*)d_in[1];
    const float* vals     = (const float*)d_in[2];
    const float* user_emb = (const float*)d_in[3];
    const float* item_emb = (const float*)d_in[4];
    float* acc = (float*)d_out;

    // ws layout (u32 units):
    //   buf0 bf16 [4.8M] | stage_key [6.0M] | stage_val u16 [3.0M u32]
    //   | csr_col [4.8M] | csr_val u16 [2.4M u32] | row_beg [150K] | row_cnt [150K]
    //   | bx_pos [4688*16] | csr_cursor [16]
    //   buf1 bf16 aliases stage_key (stage dead after stageB2).
    constexpr size_t U_BUF  = (size_t)NODE_FLOATS / 2;    // 4,800,000
    constexpr size_t U_SKEY = (size_t)SEG * CAP1;         // 6,000,640
    constexpr size_t U_SVAL = U_SKEY / 2;                 // 3,000,320
    constexpr size_t U_CCOL = (size_t)N_EDGES;            // 4,800,000
    constexpr size_t U_CVAL = (size_t)N_EDGES / 2;        // 2,400,000
    size_t need_u32 = U_BUF + U_SKEY + U_SVAL + U_CCOL + U_CVAL
                    + 2 * (size_t)N_NODES + (size_t)SEG * 16 + 16;

    const int EW_BLOCKS = (NODE_FLOAT4S + 255) / 256;

    if (ws_size >= need_u32 * 4) {
        u32* W = (u32*)d_ws;
        u16* buf0      = (u16*)W;
        u32* stage_key = W + U_BUF;
        u16* stage_val = (u16*)(W + U_BUF + U_SKEY);
        u16* buf1      = (u16*)stage_key;                 // alias
        u32* csr_col   = W + U_BUF + U_SKEY + U_SVAL;
        u16* csr_val   = (u16*)(csr_col + U_CCOL);
        int* row_beg   = (int*)(csr_col + U_CCOL + U_CVAL);
        int* row_cnt   = row_beg + N_NODES;
        int* bx_pos    = row_cnt + N_NODES;
        int* csr_cur   = bx_pos + (size_t)SEG * 16;

        init_ptrs_kernel<<<(SEG + 255) / 256, 256, 0, stream>>>(bx_pos, csr_cur);
        init_kernel<<<EW_BLOCKS, 256, 0, stream>>>(user_emb, item_emb, buf0, acc);
        stageA2_kernel<<<ABLK2, 256, 0, stream>>>(rows, cols, vals, bx_pos,
                                                  stage_key, stage_val);
        stageB2_kernel<<<NB, 256, 0, stream>>>(bx_pos, stage_key, stage_val,
                                               csr_cur, csr_col, csr_val,
                                               row_beg, row_cnt);

        const int SPMM_BLOCKS = (N_NODES * 16 + 255) / 256;
        spmm_csr_kernel<<<SPMM_BLOCKS, 256, 0, stream>>>(row_beg, row_cnt, csr_col, csr_val,
                                                         buf0, buf1, acc, 1.0f);
        spmm_csr_kernel<<<SPMM_BLOCKS, 256, 0, stream>>>(row_beg, row_cnt, csr_col, csr_val,
                                                         buf1, buf0, acc, 1.0f);
        spmm_csr_kernel<<<SPMM_BLOCKS, 256, 0, stream>>>(row_beg, row_cnt, csr_col, csr_val,
                                                         buf0, nullptr, acc, 0.25f);
    } else {
        // fallback: R0 atomic path
        float* buf0 = (float*)d_ws;
        float* buf1 = buf0 + NODE_FLOATS;
        const int SPMM_BLOCKS = (int)(((size_t)N_EDGES * 16 + 255) / 256);
        init3_kernel<<<EW_BLOCKS, 256, 0, stream>>>(user_emb, item_emb, buf0, acc, buf1);
        float* prev = buf0; float* next = buf1;
        for (int layer = 0; layer < 3; ++layer) {
            spmm_atomic_kernel<<<SPMM_BLOCKS, 256, 0, stream>>>(rows, cols, vals, prev, next);
            if (layer < 2) acc_kernel<<<EW_BLOCKS, 256, 0, stream>>>(acc, next, prev, 1, 1.0f);
            else           acc_kernel<<<EW_BLOCKS, 256, 0, stream>>>(acc, next, prev, 0, 0.25f);
            float* t = prev; prev = next; next = t;
        }
    }
}